// Round 1
// baseline (143.816 us; speedup 1.0000x reference)
//
#include <hip/hip_runtime.h>
#include <hip/hip_bf16.h>

// AVWGCN: per-node graph conv. N=10000 nodes, C=HID=64, B=32, K=2.
// One 256-thread block (4 waves) per node:
//   Phase A: softmax(relu(E[n])) row-wise -> St (transposed, fp32, LDS)
//   Phase B: XG1 = X @ S via MFMA (X frags direct from global) -> LDS
//   Phase C: OUT = X@W0 + XG1@W1 + bias via MFMA (W frags direct from global)

constexpr int N_ = 10000;
constexpr int C_ = 64;
constexpr int H_ = 64;
constexpr int B_ = 32;
constexpr int STP = 67;   // odd LDS stride (fp32 elems): <=2-way bank conflicts

typedef __bf16 bf16x8 __attribute__((ext_vector_type(8)));
typedef float  f32x4  __attribute__((ext_vector_type(4)));

__global__ __launch_bounds__(256, 2) void avwgcn_kernel(
    const float* __restrict__ x,      // (B, N, C)
    const float* __restrict__ emb,    // (N, C, C)
    const float* __restrict__ wpool,  // (K, N, C, H)
    const float* __restrict__ bias,   // (N, H)
    float* __restrict__ out)          // (B, N, H)
{
    __shared__ float st[64 * STP];    // st[m][c] = S[c][m]  (S = softmax(relu(E)))
    __shared__ float g1[32 * STP];    // g1[b][m] = XG1[b][m]

    const int n = blockIdx.x;
    const int t = threadIdx.x;
    const int w = t >> 6;     // wave 0..3 -> owns output cols w*16..w*16+15
    const int l = t & 63;
    const int r = l & 15;     // frag row/col within tile
    const int g = l >> 4;     // k-group 0..3

    // ---------------- Phase A: row-wise softmax(relu(E[n])) ----------------
    {
        const int c = t >> 2;   // row of E (0..63)
        const int q = t & 3;    // 16-wide column segment
        const float* ep = emb + (size_t)n * (C_ * C_) + c * C_ + q * 16;
        float v[16];
        #pragma unroll
        for (int i = 0; i < 4; ++i) {
            float4 e4 = *reinterpret_cast<const float4*>(ep + i * 4);
            v[i * 4 + 0] = e4.x; v[i * 4 + 1] = e4.y;
            v[i * 4 + 2] = e4.z; v[i * 4 + 3] = e4.w;
        }
        float s = 0.f;
        #pragma unroll
        for (int i = 0; i < 16; ++i) {
            float e = __expf(fmaxf(v[i], 0.f));  // relu values <= ~6, no overflow
            v[i] = e;
            s += e;
        }
        // quad (lanes t^1, t^2) holds the other 48 columns of this row
        s += __shfl_xor(s, 1);
        s += __shfl_xor(s, 2);
        const float inv = 1.0f / s;
        #pragma unroll
        for (int i = 0; i < 16; ++i)
            st[(q * 16 + i) * STP + c] = v[i] * inv;   // transposed store
    }

    // X A-frags direct from global (reused for X@S and X@W0):
    // A[row=r][k=(g*8+i)+kt*32], row = mt*16+r is the batch index.
    bf16x8 xa[2][2];
    #pragma unroll
    for (int mt = 0; mt < 2; ++mt) {
        #pragma unroll
        for (int kt = 0; kt < 2; ++kt) {
            const float* xp = x + (size_t)(mt * 16 + r) * (N_ * C_)
                                + (size_t)n * C_ + kt * 32 + g * 8;
            float4 a0 = *reinterpret_cast<const float4*>(xp);
            float4 a1 = *reinterpret_cast<const float4*>(xp + 4);
            bf16x8 f;
            f[0] = (__bf16)a0.x; f[1] = (__bf16)a0.y;
            f[2] = (__bf16)a0.z; f[3] = (__bf16)a0.w;
            f[4] = (__bf16)a1.x; f[5] = (__bf16)a1.y;
            f[6] = (__bf16)a1.z; f[7] = (__bf16)a1.w;
            xa[mt][kt] = f;
        }
    }

    __syncthreads();

    // ---------------- Phase B: XG1 = X @ S ----------------
    f32x4 accg[2];
    accg[0] = (f32x4){0.f, 0.f, 0.f, 0.f};
    accg[1] = (f32x4){0.f, 0.f, 0.f, 0.f};
    #pragma unroll
    for (int kt = 0; kt < 2; ++kt) {
        // B-frag: S[k=c][col=m], col = w*16+r, k = kt*32+g*8+i -> st rows
        const float* sp = st + (w * 16 + r) * STP + kt * 32 + g * 8;
        bf16x8 sb;
        #pragma unroll
        for (int i = 0; i < 8; ++i) sb[i] = (__bf16)sp[i];
        #pragma unroll
        for (int mt = 0; mt < 2; ++mt)
            accg[mt] = __builtin_amdgcn_mfma_f32_16x16x32_bf16(
                xa[mt][kt], sb, accg[mt], 0, 0, 0);
    }

    // C/D layout: col = lane&15, row = g*4 + reg -> scatter into g1[b][m]
    #pragma unroll
    for (int mt = 0; mt < 2; ++mt)
        #pragma unroll
        for (int ri = 0; ri < 4; ++ri)
            g1[(mt * 16 + g * 4 + ri) * STP + (w * 16 + r)] = accg[mt][ri];

    __syncthreads();

    // ---------------- Phase C: OUT = X@W0 + XG1@W1 + bias ----------------
    // XG1 A-frags from LDS
    bf16x8 ga[2][2];
    #pragma unroll
    for (int mt = 0; mt < 2; ++mt) {
        #pragma unroll
        for (int kt = 0; kt < 2; ++kt) {
            const float* gp = g1 + (mt * 16 + r) * STP + kt * 32 + g * 8;
            bf16x8 f;
            #pragma unroll
            for (int i = 0; i < 8; ++i) f[i] = (__bf16)gp[i];
            ga[mt][kt] = f;
        }
    }

    f32x4 acc[2];
    acc[0] = (f32x4){0.f, 0.f, 0.f, 0.f};
    acc[1] = (f32x4){0.f, 0.f, 0.f, 0.f};

    const float* w0 = wpool + (size_t)n * (C_ * H_);
    const float* w1 = wpool + ((size_t)N_ + n) * (C_ * H_);

    #pragma unroll
    for (int kt = 0; kt < 2; ++kt) {
        // B-frag of W0: W0[k=m][col=o], col = w*16+r, k = kt*32+g*8+i (stride H_)
        const float* wp = w0 + (size_t)(kt * 32 + g * 8) * H_ + w * 16 + r;
        bf16x8 wb;
        #pragma unroll
        for (int i = 0; i < 8; ++i) wb[i] = (__bf16)wp[i * H_];
        #pragma unroll
        for (int mt = 0; mt < 2; ++mt)
            acc[mt] = __builtin_amdgcn_mfma_f32_16x16x32_bf16(
                xa[mt][kt], wb, acc[mt], 0, 0, 0);
    }
    #pragma unroll
    for (int kt = 0; kt < 2; ++kt) {
        const float* wp = w1 + (size_t)(kt * 32 + g * 8) * H_ + w * 16 + r;
        bf16x8 wb;
        #pragma unroll
        for (int i = 0; i < 8; ++i) wb[i] = (__bf16)wp[i * H_];
        #pragma unroll
        for (int mt = 0; mt < 2; ++mt)
            acc[mt] = __builtin_amdgcn_mfma_f32_16x16x32_bf16(
                ga[mt][kt], wb, acc[mt], 0, 0, 0);
    }

    // Epilogue: add per-node bias, store.
    const float bv = bias[(size_t)n * H_ + w * 16 + r];
    #pragma unroll
    for (int mt = 0; mt < 2; ++mt) {
        #pragma unroll
        for (int ri = 0; ri < 4; ++ri) {
            const int b = mt * 16 + g * 4 + ri;
            const int o = w * 16 + r;
            out[(size_t)b * (N_ * H_) + (size_t)n * H_ + o] = acc[mt][ri] + bv;
        }
    }
}

extern "C" void kernel_launch(void* const* d_in, const int* in_sizes, int n_in,
                              void* d_out, int out_size, void* d_ws, size_t ws_size,
                              hipStream_t stream) {
    const float* x    = (const float*)d_in[0];
    const float* emb  = (const float*)d_in[1];
    const float* wp   = (const float*)d_in[2];
    const float* bias = (const float*)d_in[3];
    float* out = (float*)d_out;
    avwgcn_kernel<<<N_, 256, 0, stream>>>(x, emb, wp, bias, out);
}